// Round 1
// baseline (1920.102 us; speedup 1.0000x reference)
//
#include <hip/hip_runtime.h>

#define DEVINL __device__ __forceinline__

static constexpr int BLK = 256;

DEVINL float sigmoidf_(float x) { return 1.0f / (1.0f + __expf(-x)); }
// stable tanh: large +x -> exp=inf -> 1-0 = 1; large -x -> exp=0 -> 1-2 = -1
DEVINL float tanh_fast(float x) { return 1.0f - 2.0f / (__expf(2.0f * x) + 1.0f); }

__global__ void zero_kernel(float* __restrict__ deg, int* __restrict__ cnt,
                            int* __restrict__ fillcnt, int N) {
  int i = blockIdx.x * blockDim.x + threadIdx.x;
  if (i < N) { deg[i] = 0.0f; cnt[i] = 0; fillcnt[i] = 0; }
}

// feat_n = feat / rowsum(feat); write to featn (for LSTM windows) and buf0 cols [0,8)
__global__ void norm_kernel(const float* __restrict__ feat, float* __restrict__ featn,
                            float* __restrict__ buf0, int N) {
  int n = blockIdx.x * blockDim.x + threadIdx.x;
  if (n >= N) return;
  const float4* fp = (const float4*)(feat + (size_t)n * 8);
  float4 a = fp[0], b = fp[1];
  float s = a.x + a.y + a.z + a.w + b.x + b.y + b.z + b.w;
  float r = 1.0f / s;
  a.x *= r; a.y *= r; a.z *= r; a.w *= r;
  b.x *= r; b.y *= r; b.z *= r; b.w *= r;
  float4* on = (float4*)(featn + (size_t)n * 8);
  on[0] = a; on[1] = b;
  float4* o0 = (float4*)(buf0 + (size_t)n * 24);
  o0[0] = a; o0[1] = b;
}

// one thread per node; 5-step LSTM over window feat_n[max(0,n-5) .. ), right-zero-padded.
// writes h_last into buf0 cols [8,24)
__global__ void lstm_kernel(const float* __restrict__ featn,
                            const float* __restrict__ W_ih, const float* __restrict__ W_hh,
                            const float* __restrict__ b_ih, const float* __restrict__ b_hh,
                            float* __restrict__ buf0, int N) {
  __shared__ float sWih[64 * 8];
  __shared__ float sWhh[64 * 16];
  __shared__ float sb[64];
  for (int i = threadIdx.x; i < 64 * 8; i += blockDim.x) sWih[i] = W_ih[i];
  for (int i = threadIdx.x; i < 64 * 16; i += blockDim.x) sWhh[i] = W_hh[i];
  for (int i = threadIdx.x; i < 64; i += blockDim.x) sb[i] = b_ih[i] + b_hh[i];
  __syncthreads();
  int n = blockIdx.x * blockDim.x + threadIdx.x;
  if (n >= N) return;
  float h[16], c[16];
#pragma unroll
  for (int j = 0; j < 16; ++j) { h[j] = 0.0f; c[j] = 0.0f; }
  const int start = (n >= 5) ? (n - 5) : 0;
  const int nvalid = (n < 5) ? n : 5;
#pragma unroll
  for (int t = 0; t < 5; ++t) {
    float x[8];
    if (t < nvalid) {
      const float4* xr = (const float4*)(featn + (size_t)(start + t) * 8);
      float4 x0 = xr[0], x1 = xr[1];
      x[0] = x0.x; x[1] = x0.y; x[2] = x0.z; x[3] = x0.w;
      x[4] = x1.x; x[5] = x1.y; x[6] = x1.z; x[7] = x1.w;
    } else {
#pragma unroll
      for (int k = 0; k < 8; ++k) x[k] = 0.0f;
    }
    float hn[16];
#pragma unroll
    for (int j = 0; j < 16; ++j) {
      float gi = sb[j], gf = sb[16 + j], gg = sb[32 + j], go = sb[48 + j];
#pragma unroll
      for (int k = 0; k < 8; ++k) {
        gi += x[k] * sWih[j * 8 + k];
        gf += x[k] * sWih[(16 + j) * 8 + k];
        gg += x[k] * sWih[(32 + j) * 8 + k];
        go += x[k] * sWih[(48 + j) * 8 + k];
      }
#pragma unroll
      for (int k = 0; k < 16; ++k) {
        gi += h[k] * sWhh[j * 16 + k];
        gf += h[k] * sWhh[(16 + j) * 16 + k];
        gg += h[k] * sWhh[(32 + j) * 16 + k];
        go += h[k] * sWhh[(48 + j) * 16 + k];
      }
      float cn = sigmoidf_(gf) * c[j] + sigmoidf_(gi) * tanh_fast(gg);
      c[j] = cn;
      hn[j] = sigmoidf_(go) * tanh_fast(cn);
    }
#pragma unroll
    for (int j = 0; j < 16; ++j) h[j] = hn[j];
  }
  float* out = buf0 + (size_t)n * 24 + 8;
#pragma unroll
  for (int j = 0; j < 16; ++j) out[j] = h[j];
}

__global__ void deg_kernel(const int* __restrict__ src, const float* __restrict__ w,
                           float* __restrict__ deg, int E) {
  int e = blockIdx.x * blockDim.x + threadIdx.x;
  if (e < E) atomicAdd(&deg[src[e]], w[e]);
}

__global__ void count_kernel(const int* __restrict__ dst, int* __restrict__ cnt, int E) {
  int e = blockIdx.x * blockDim.x + threadIdx.x;
  if (e < E) atomicAdd(&cnt[dst[e]], 1);
}

// single-block exclusive scan of cnt[N] -> rowptr[N+1]
__global__ void scan_kernel(const int* __restrict__ cnt, int* __restrict__ rowptr,
                            int N, int E) {
  __shared__ int part[1024];
  int t = threadIdx.x;
  int chunk = (N + 1023) / 1024;
  int lo = t * chunk;
  int hi = lo + chunk; if (hi > N) hi = N; if (lo > N) lo = N;
  int s = 0;
  for (int i = lo; i < hi; ++i) s += cnt[i];
  part[t] = s;
  __syncthreads();
  for (int d = 1; d < 1024; d <<= 1) {
    int v = (t >= d) ? part[t - d] : 0;
    __syncthreads();
    part[t] += v;
    __syncthreads();
  }
  int run = (t == 0) ? 0 : part[t - 1];
  for (int i = lo; i < hi; ++i) { rowptr[i] = run; run += cnt[i]; }
  if (t == 0) rowptr[N] = E;
}

__global__ void fill_kernel(const int* __restrict__ src, const int* __restrict__ dst,
                            const float* __restrict__ w, const float* __restrict__ deg,
                            const int* __restrict__ rowptr, int* __restrict__ fillcnt,
                            int* __restrict__ col, float* __restrict__ wcsr, int E) {
  int e = blockIdx.x * blockDim.x + threadIdx.x;
  if (e >= E) return;
  int d = dst[e], s = src[e];
  int pos = atomicAdd(&fillcnt[d], 1);
  int idx = rowptr[d] + pos;
  col[idx] = s;
  wcsr[idx] = w[e] * rsqrtf(deg[s] * deg[d]);
}

// M[row, col] = sum_k X[row,k] * W[k,col]
template <int DIN, int DOUT>
__global__ void gemm_kernel(const float* __restrict__ X, const float* __restrict__ W,
                            float* __restrict__ M, int N) {
  int gid = blockIdx.x * blockDim.x + threadIdx.x;
  int row = gid / DOUT, cj = gid % DOUT;
  if (row >= N) return;
  const float* xr = X + (size_t)row * DIN;
  float acc = 0.0f;
#pragma unroll
  for (int k = 0; k < DIN; ++k) acc += xr[k] * W[k * DOUT + cj];
  M[(size_t)row * DOUT + cj] = acc;
}

// out[row, lane] = act( sum_{e in CSR row} wcsr[e]*m[col[e], lane] + bias[lane] )
template <int DOUT, bool ACT>
__global__ void gather_kernel(const float* __restrict__ m, const int* __restrict__ rowptr,
                              const int* __restrict__ col, const float* __restrict__ wcsr,
                              const float* __restrict__ bias, float* __restrict__ out, int N) {
  int gid = blockIdx.x * blockDim.x + threadIdx.x;
  int row = gid / DOUT, lane = gid % DOUT;
  if (row >= N) return;
  int lo = rowptr[row], hi = rowptr[row + 1];
  float acc = 0.0f;
  for (int e = lo; e < hi; ++e) {
    int s = col[e];
    float w = wcsr[e];
    acc += w * m[(size_t)s * DOUT + lane];
  }
  acc += bias[lane];
  if (ACT) acc = (acc >= 0.0f) ? acc : 0.01f * acc;
  out[(size_t)row * DOUT + lane] = acc;
}

extern "C" void kernel_launch(void* const* d_in, const int* in_sizes, int n_in,
                              void* d_out, int out_size, void* d_ws, size_t ws_size,
                              hipStream_t stream) {
  const float* feat = (const float*)d_in[0];
  const int* esrc   = (const int*)d_in[1];
  const int* edst   = (const int*)d_in[2];
  const float* ew   = (const float*)d_in[3];
  const float* W_ih = (const float*)d_in[4];
  const float* W_hh = (const float*)d_in[5];
  const float* b_ih = (const float*)d_in[6];
  const float* b_hh = (const float*)d_in[7];
  const float* W0   = (const float*)d_in[8];
  const float* b0   = (const float*)d_in[9];
  const float* W1   = (const float*)d_in[10];
  const float* b1   = (const float*)d_in[11];
  const float* W2   = (const float*)d_in[12];
  const float* b2   = (const float*)d_in[13];
  const int N = in_sizes[0] / 8;
  const int E = in_sizes[1];
  float* out = (float*)d_out;

  // workspace layout (floats): buf0[N*24] | bufM[N*64] | bufA[N*64] | deg[N] |
  //                            rowptr[N+1] | col[E] | wcsr[E]     (~74 MB total)
  float* buf0 = (float*)d_ws;
  float* bufM = buf0 + (size_t)N * 24;
  float* bufA = bufM + (size_t)N * 64;
  float* deg  = bufA + (size_t)N * 64;
  int* rowptr = (int*)(deg + N);
  int* col    = rowptr + (N + 1);
  float* wcsr = (float*)(col + E);
  // aliases: cnt/fillcnt live in bufM (dead before GEMM0 writes it);
  //          featn lives in bufA (dead before gather0 writes it)
  int* cnt     = (int*)bufM;
  int* fillcnt = cnt + N;
  float* featn = bufA;

  const int gN = (N + BLK - 1) / BLK;
  const int gE = (E + BLK - 1) / BLK;
  const int gN64 = (N * 64 + BLK - 1) / BLK;
  const int gN32 = (N * 32 + BLK - 1) / BLK;

  zero_kernel<<<gN, BLK, 0, stream>>>(deg, cnt, fillcnt, N);
  norm_kernel<<<gN, BLK, 0, stream>>>(feat, featn, buf0, N);
  lstm_kernel<<<gN, BLK, 0, stream>>>(featn, W_ih, W_hh, b_ih, b_hh, buf0, N);
  deg_kernel<<<gE, BLK, 0, stream>>>(esrc, ew, deg, E);
  count_kernel<<<gE, BLK, 0, stream>>>(edst, cnt, E);
  scan_kernel<<<1, 1024, 0, stream>>>(cnt, rowptr, N, E);
  fill_kernel<<<gE, BLK, 0, stream>>>(esrc, edst, ew, deg, rowptr, fillcnt, col, wcsr, E);

  gemm_kernel<24, 64><<<gN64, BLK, 0, stream>>>(buf0, W0, bufM, N);
  gather_kernel<64, true><<<gN64, BLK, 0, stream>>>(bufM, rowptr, col, wcsr, b0, bufA, N);
  gemm_kernel<64, 64><<<gN64, BLK, 0, stream>>>(bufA, W1, bufM, N);
  gather_kernel<64, true><<<gN64, BLK, 0, stream>>>(bufM, rowptr, col, wcsr, b1, bufA, N);
  gemm_kernel<64, 32><<<gN32, BLK, 0, stream>>>(bufA, W2, bufM, N);
  gather_kernel<32, false><<<gN32, BLK, 0, stream>>>(bufM, rowptr, col, wcsr, b2, out, N);
}